// Round 1
// baseline (247.084 us; speedup 1.0000x reference)
//
#include <hip/hip_runtime.h>
#include <hip/hip_bf16.h>

// N=4, C=256, H=W=64 -> HW=4096, E=128, 3E=384.
// qkv flat [n][o][hw] IS [n][p][384]: q=p*384+0..127, k=+128, v=+256.
// attn flat [n][i*128+d] reinterpreted as [n][e][hw] by k_oproj (raw reshape).
// Column softmax (over i): scores s=q.k/64, |s|<~1.2 -> direct sum-exp (no max).
// R9: 1/Z folded into V (vt_scaled = v[j][d]/Z[j]) -> no Ls in k_attn -> LDS 54,272 B
//     = 53 KiB exactly -> 3 blocks/CU; j-chunk split 4->8 (1024 blocks) to fill them.

typedef short bfrag __attribute__((ext_vector_type(8)));   // 8 bf16 (4 VGPRs)
typedef float ffrag __attribute__((ext_vector_type(4)));   // 4 fp32 acc
typedef unsigned short us4 __attribute__((ext_vector_type(4)));
#define MFMA(a,b,c) __builtin_amdgcn_mfma_f32_16x16x32_bf16((a),(b),(c),0,0,0)

__device__ __forceinline__ unsigned short f2bf(float f){
  union { float f; unsigned u; } v; v.f = f;
  unsigned r = v.u + 0x7fffu + ((v.u >> 16) & 1u);   // RNE
  return (unsigned short)(r >> 16);
}
__device__ __forceinline__ float bf2f(unsigned short h){
  union { unsigned u; float f; } v; v.u = ((unsigned)h) << 16; return v.f;
}
__device__ __forceinline__ unsigned bfpack(float a, float b){
  return (unsigned)f2bf(a) | ((unsigned)f2bf(b) << 16);
}

// ---------------- K0: cast weights to bf16 ----------------
__global__ __launch_bounds__(256) void k_wcast(const float* __restrict__ Wq, const float* __restrict__ Wo,
                                               unsigned short* __restrict__ Wqb, unsigned short* __restrict__ Wob){
  int i = blockIdx.x*256 + threadIdx.x;
  if (i < 384*256) Wqb[i] = f2bf(Wq[i]);
  if (i < 256*128) Wob[i] = f2bf(Wo[i]);
}

// ---------------- K1: QKV projection, o-tile 128 (x re-read 3x instead of 6x) ----------------
__global__ __launch_bounds__(256) void k_qkv(const float* __restrict__ x, const unsigned short* __restrict__ Wqb,
                                             const float* __restrict__ bq, unsigned short* __restrict__ qkv){
  constexpr int LD = 136;
  __shared__ __align__(16) unsigned short As[128*LD];  // W tile [o 128][c-half 128]  34816 B
  __shared__ __align__(16) unsigned short Bs[64*LD];   // X^T tile [hw 64][c-half]    17408 B
  const int o0 = blockIdx.x*128, h0 = blockIdx.y*64, n = blockIdx.z;
  const int t = threadIdx.x, w = t>>6, lane = t&63, lr = lane&15, q4 = lane>>4;
  ffrag acc[8] = {};
  for (int kh = 0; kh < 2; ++kh) {
    __syncthreads();
    #pragma unroll
    for (int r=0;r<8;++r){                       // 2048 = 128 o x 16 segs
      int pi = t + 256*r; int o = pi>>4, seg = pi&15;
      *(uint4*)&As[o*LD + seg*8] = *(const uint4*)(Wqb + (o0+o)*256 + kh*128 + seg*8);
    }
    #pragma unroll
    for (int r=0;r<8;++r){                       // 2048 = 128 c x 16 h-quads, float4 loads
      int idx = t + 256*r; int cl = idx>>4, h4 = idx&15;
      float4 v = *(const float4*)(x + (size_t)(n*256 + kh*128 + cl)*4096 + h0 + h4*4);
      Bs[(h4*4+0)*LD + cl] = f2bf(v.x);
      Bs[(h4*4+1)*LD + cl] = f2bf(v.y);
      Bs[(h4*4+2)*LD + cl] = f2bf(v.z);
      Bs[(h4*4+3)*LD + cl] = f2bf(v.w);
    }
    __syncthreads();
    #pragma unroll
    for (int kk=0;kk<4;++kk){
      bfrag a = *(const bfrag*)&Bs[(w*16+lr)*LD + kk*32 + q4*8];   // A = x^T rows (hw)
      #pragma unroll
      for (int ot=0;ot<8;++ot){
        bfrag b = *(const bfrag*)&As[(ot*16+lr)*LD + kk*32 + q4*8]; // B = W rows (o)
        acc[ot] = MFMA(a,b,acc[ot]);                                // D[m=hw][n=o]
      }
    }
  }
  size_t base = (size_t)n*384*4096;
  #pragma unroll
  for (int ot=0;ot<8;++ot){
    int o  = o0 + ot*16 + lr;
    float bias = bq[o];
    int hw = h0 + w*16 + q4*4;
    us4 pk;
    pk.x = f2bf(acc[ot][0] + bias); pk.y = f2bf(acc[ot][1] + bias);
    pk.z = f2bf(acc[ot][2] + bias); pk.w = f2bf(acc[ot][3] + bias);
    *(us4*)(qkv + base + (size_t)o*4096 + hw) = pk;
  }
}

// ---------------- K2: column Z partials, wave owns 64 j (16 reg K-frags, 4 MFMA per Q read) ----------------
__global__ __launch_bounds__(256) void k_stats(const unsigned short* __restrict__ qkv,
                                               float* __restrict__ zp){
  constexpr int LD = 136;
  __shared__ __align__(16) unsigned short Qs[64*LD];   // 17408 B
  const int j0 = blockIdx.x*256, ic = blockIdx.y, n = blockIdx.z;
  const int t = threadIdx.x, w = t>>6, lane = t&63, lr = lane&15, q4 = lane>>4;
  size_t base = (size_t)n*384*4096;
  bfrag kf[4][4];
  #pragma unroll
  for (int js=0; js<4; ++js){
    const unsigned short* krow = qkv + base + (size_t)(j0 + w*64 + js*16 + lr)*384 + 128;
    #pragma unroll
    for (int kk=0;kk<4;++kk) kf[js][kk] = *(const bfrag*)(krow + kk*32 + q4*8);
  }
  float Zc[16] = {};                      // [js*4 + r]
  const float inv64 = 0.015625f;
  for (int rnd=0; rnd<8; ++rnd){          // 8 x 64-i stage rounds (ic chunk = 512 i)
    int i0 = (ic<<9) + rnd*64;
    __syncthreads();
    #pragma unroll
    for (int r=0;r<4;++r){
      int pi = t + 256*r; int il = pi>>4, seg = pi&15;
      *(uint4*)&Qs[il*LD + seg*8] = *(const uint4*)(qkv + base + (size_t)(i0+il)*384 + seg*8);
    }
    __syncthreads();
    #pragma unroll
    for (int it=0; it<4; ++it){
      bfrag qb[4];
      #pragma unroll
      for (int kk=0;kk<4;++kk) qb[kk] = *(const bfrag*)&Qs[(it*16+lr)*LD + kk*32 + q4*8];
      #pragma unroll
      for (int js=0; js<4; ++js){
        ffrag s = {};
        #pragma unroll
        for (int kk=0;kk<4;++kk) s = MFMA(kf[js][kk], qb[kk], s);   // D[m=j][n=i]
        #pragma unroll
        for (int r=0;r<4;++r) Zc[js*4+r] += __expf(s[r]*inv64);
      }
    }
  }
  #pragma unroll
  for (int v=0; v<16; ++v){
    float z = Zc[v];
    z += __shfl_xor(z, 1); z += __shfl_xor(z, 2);
    z += __shfl_xor(z, 4); z += __shfl_xor(z, 8);
    Zc[v] = z;
  }
  if (lr == 0){
    int jb = j0 + w*64;
    float* zrow = zp + (size_t)((n<<3)+ic)*4096;
    #pragma unroll
    for (int js=0; js<4; ++js)
      #pragma unroll
      for (int r=0;r<4;++r)
        zrow[jb + js*16 + q4*4 + r] = Zc[js*4+r];
  }
}

// ---------------- K3: V transpose + Z-merge + 1/Z fold: vt[n][d][p] = v[n][p][d] / Z[p] ----------------
__global__ __launch_bounds__(256) void k_vtrans(const unsigned short* __restrict__ qkv,
                                                const float* __restrict__ zp,
                                                unsigned short* __restrict__ vt){
  constexpr int LD = 136;
  __shared__ __align__(16) unsigned short T[64*LD];
  __shared__ float invZ[64];
  const int p0 = blockIdx.x*64, n = blockIdx.y;
  const int t = threadIdx.x;
  size_t base = (size_t)n*384*4096;
  #pragma unroll
  for (int r=0;r<4;++r){
    int pi = t + 256*r; int pl = pi>>4, seg = pi&15;
    *(uint4*)&T[pl*LD + seg*8] = *(const uint4*)(qkv + base + (size_t)(p0+pl)*384 + 256 + seg*8);
  }
  if (t < 64){                            // merge zp partials for this block's 64 j
    float Z = 0.f;
    #pragma unroll
    for (int c=0;c<8;++c) Z += zp[(size_t)((n<<3)+c)*4096 + p0 + t];
    invZ[t] = 1.0f / Z;
  }
  __syncthreads();
  unsigned* vt32 = (unsigned*)(vt + (size_t)n*128*4096);
  #pragma unroll
  for (int r=0;r<16;++r){
    int pi = t + 256*r;            // 4096 = 128 d x 32 p-pairs
    int d = pi>>5, k = pi&31;
    float lo = bf2f(T[(2*k)*LD + d])   * invZ[2*k];
    float hi = bf2f(T[(2*k+1)*LD + d]) * invZ[2*k+1];
    vt32[(size_t)d*2048 + (p0>>1) + k] = bfpack(lo, hi);
  }
}

// ---------------- K4: PV pass — no Ls (1/Z pre-folded into Vt) -> 53 KiB LDS -> 3 blocks/CU ----------------
__global__ __launch_bounds__(256) void k_attn(const unsigned short* __restrict__ qkv,
                                              const unsigned short* __restrict__ vtg_all,
                                              unsigned short* __restrict__ part,
                                              int JCH){
  constexpr int LDK = 136, LDV = 72, LDP = 72;
  __shared__ __align__(16) unsigned short Ks[64*LDK];    // 17408 B
  __shared__ __align__(16) unsigned short Vt[128*LDV];   // 18432 B
  __shared__ __align__(16) unsigned short Pw[4][32*LDP]; // 18432 B   total 54272 = 53 KiB
  const int i0 = blockIdx.x*128, jh = blockIdx.y, n = blockIdx.z;
  const int t = threadIdx.x, w = t>>6, lane = t&63, lr = lane&15, q4 = lane>>4;
  size_t base = (size_t)n*384*4096;
  const unsigned short* vtg = vtg_all + (size_t)n*128*4096;
  bfrag qf[2][4];   // B[k=d][n=i] for 2 i-subtiles (register-resident)
  #pragma unroll
  for (int isub=0;isub<2;++isub){
    const unsigned short* qrow = qkv + base + (size_t)(i0 + w*32 + isub*16 + lr)*384;
    #pragma unroll
    for (int kk=0;kk<4;++kk) qf[isub][kk] = *(const bfrag*)(qrow + kk*32 + q4*8);
  }
  ffrag acc[8][2] = {};
  const float inv64 = 0.015625f;
  for (int j0 = jh*JCH; j0 < jh*JCH + JCH; j0 += 64){
    __syncthreads();
    #pragma unroll
    for (int r=0;r<4;++r){                    // K rows j0..j0+63
      int pi = t + 256*r; int jl = pi>>4, seg = pi&15;
      *(uint4*)&Ks[jl*LDK + seg*8] = *(const uint4*)(qkv + base + (size_t)(j0+jl)*384 + 128 + seg*8);
    }
    #pragma unroll
    for (int r=0;r<4;++r){                    // Vt[128 d][64 j] (pre-scaled by 1/Z[j])
      int pi = t + 256*r; int d = pi>>3, c = pi&7;
      *(uint4*)&Vt[d*LDV + c*8] = *(const uint4*)(vtg + (size_t)d*4096 + j0 + c*8);
    }
    __syncthreads();
    #pragma unroll
    for (int jt=0;jt<4;++jt){
      bfrag kf[4];
      #pragma unroll
      for (int kk=0;kk<4;++kk) kf[kk] = *(const bfrag*)&Ks[(jt*16+lr)*LDK + kk*32 + q4*8]; // A[m=j][k=d]
      #pragma unroll
      for (int isub=0;isub<2;++isub){         // each K-frag feeds 2 MFMA chains
        ffrag s = {};
        #pragma unroll
        for (int kk=0;kk<4;++kk) s = MFMA(kf[kk], qf[isub][kk], s);   // D[m=j][n=i]
        float p0 = __expf(s[0]*inv64);
        float p1 = __expf(s[1]*inv64);
        float p2 = __expf(s[2]*inv64);
        float p3 = __expf(s[3]*inv64);
        uint2 pk; pk.x = bfpack(p0,p1); pk.y = bfpack(p2,p3);
        *(uint2*)&Pw[w][(isub*16+lr)*LDP + jt*16 + q4*4] = pk;   // wave-private
      }
    }
    asm volatile("" ::: "memory");             // no compiler reorder of Pw read above writes
    #pragma unroll
    for (int jk=0;jk<2;++jk){
      bfrag pf0 = *(const bfrag*)&Pw[w][lr*LDP      + jk*32 + q4*8];  // B[k=j][n=i] isub 0
      bfrag pf1 = *(const bfrag*)&Pw[w][(16+lr)*LDP + jk*32 + q4*8];  // isub 1
      #pragma unroll
      for (int dt=0;dt<8;++dt){
        bfrag af = *(const bfrag*)&Vt[(dt*16+lr)*LDV + jk*32 + q4*8]; // A[m=d][k=j], feeds 2 MFMAs
        acc[dt][0] = MFMA(af, pf0, acc[dt][0]);   // D[m=d][n=i]
        acc[dt][1] = MFMA(af, pf1, acc[dt][1]);
      }
    }
  }
  unsigned short* po = part + (size_t)(jh*4+n)*524288;
  #pragma unroll
  for (int isub=0;isub<2;++isub){
    const int i = i0 + w*32 + isub*16 + lr;
    #pragma unroll
    for (int dt=0;dt<8;++dt){
      us4 pk;
      pk.x = f2bf(acc[dt][isub][0]); pk.y = f2bf(acc[dt][isub][1]);
      pk.z = f2bf(acc[dt][isub][2]); pk.w = f2bf(acc[dt][isub][3]);
      *(us4*)(po + (size_t)i*128 + dt*16 + q4*4) = pk;
    }
  }
}

// ---------------- K5: output projection, sums nsl bf16 partial slices (uint4 loads), c-tile 128 ----------------
__global__ __launch_bounds__(256) void k_oproj(const unsigned short* __restrict__ part,
                                               const unsigned short* __restrict__ Wob,
                                               const float* __restrict__ bo, float* __restrict__ y,
                                               int nsl){
  constexpr int LD = 136;
  __shared__ __align__(16) unsigned short As[128*LD];  // Wo tile [c][e]
  __shared__ __align__(16) unsigned short Rt[64*LD];   // attn^T [hw][e]
  const int c0 = blockIdx.x*128, h0 = blockIdx.y*64, n = blockIdx.z;
  const int t = threadIdx.x, w = t>>6, lane = t&63, lr = lane&15, q4 = lane>>4;
  #pragma unroll
  for (int r=0;r<8;++r){
    int pi = t + 256*r; int cl = pi>>4, seg = pi&15;
    *(uint4*)&As[cl*LD + seg*8] = *(const uint4*)(Wob + (c0+cl)*128 + seg*8);
  }
  #pragma unroll
  for (int r=0;r<4;++r){                     // 1024 = 128 e x 8 h-octets, uint4 loads
    int pi = t + 256*r; int e = pi>>3, h8 = pi&7;
    size_t f = (size_t)e*4096 + h0 + h8*8;
    float a[8] = {};
    for (int s=0;s<nsl;++s){
      uint4 u = *(const uint4*)(part + (size_t)(s*4+n)*524288 + f);
      a[0] += bf2f((unsigned short)(u.x & 0xffffu)); a[1] += bf2f((unsigned short)(u.x >> 16));
      a[2] += bf2f((unsigned short)(u.y & 0xffffu)); a[3] += bf2f((unsigned short)(u.y >> 16));
      a[4] += bf2f((unsigned short)(u.z & 0xffffu)); a[5] += bf2f((unsigned short)(u.z >> 16));
      a[6] += bf2f((unsigned short)(u.w & 0xffffu)); a[7] += bf2f((unsigned short)(u.w >> 16));
    }
    #pragma unroll
    for (int k=0;k<8;++k) Rt[(h8*8+k)*LD + e] = f2bf(a[k]);
  }
  __syncthreads();
  ffrag acc[8] = {};
  #pragma unroll
  for (int kk=0;kk<4;++kk){
    bfrag a = *(const bfrag*)&Rt[(w*16+lr)*LD + kk*32 + q4*8];   // A = attn^T rows (hw)
    #pragma unroll
    for (int cs=0;cs<8;++cs){
      bfrag b = *(const bfrag*)&As[(cs*16+lr)*LD + kk*32 + q4*8]; // B = Wo rows (c)
      acc[cs] = MFMA(a,b,acc[cs]);                                // D[m=hw][n=c]
    }
  }
  #pragma unroll
  for (int cs=0;cs<8;++cs){
    int c = c0 + cs*16 + lr;
    float bias = bo[c];
    float4 v4 = { acc[cs][0]+bias, acc[cs][1]+bias, acc[cs][2]+bias, acc[cs][3]+bias };
    *(float4*)(y + ((size_t)n*256 + c)*4096 + h0 + w*16 + q4*4) = v4;
  }
}

extern "C" void kernel_launch(void* const* d_in, const int* in_sizes, int n_in,
                              void* d_out, int out_size, void* d_ws, size_t ws_size,
                              hipStream_t stream){
  const float* x  = (const float*)d_in[0];
  const float* Wq = (const float*)d_in[1];
  const float* bq = (const float*)d_in[2];
  const float* Wo = (const float*)d_in[3];
  const float* bo = (const float*)d_in[4];
  float* y = (float*)d_out;
  char* ws = (char*)d_ws;
  unsigned short* qkv  = (unsigned short*)(ws + 0);          // 12,582,912
  unsigned short* vtg  = (unsigned short*)(ws + 12582912);   //  4,194,304
  unsigned short* Wqb  = (unsigned short*)(ws + 16777216);   //    196,608
  unsigned short* Wob  = (unsigned short*)(ws + 16973824);   //     65,536
  float* zp   = (float*)(ws + 17039360);                     //    524,288 (4n x 8ic x 4096)
  unsigned short* part = (unsigned short*)(ws + 17629184);   // up to 32 slices x 1 MiB (jh*4+n)

  // JH=8 needs part end at 17,629,184 + 33,554,432 = 51,183,616 bytes of ws.
  const int JH = (ws_size >= 51183616ull) ? 8 : 4;

  k_wcast <<<dim3(384),       256, 0, stream>>>(Wq, Wo, Wqb, Wob);
  k_qkv   <<<dim3(3,64,4),    256, 0, stream>>>(x, Wqb, bq, qkv);
  k_stats <<<dim3(16,8,4),    256, 0, stream>>>(qkv, zp);
  k_vtrans<<<dim3(64,4),      256, 0, stream>>>(qkv, zp, vtg);
  k_attn  <<<dim3(32,JH,4),   256, 0, stream>>>(qkv, vtg, part, 4096/JH);
  k_oproj <<<dim3(2,64,4),    256, 0, stream>>>(part, Wob, bo, y, JH*4);
}

// Round 2
// 245.716 us; speedup vs baseline: 1.0056x; 1.0056x over previous
//
#include <hip/hip_runtime.h>
#include <hip/hip_bf16.h>

// N=4, C=256, H=W=64 -> HW=4096, E=128, 3E=384.
// qkv flat [n][o][hw] IS [n][p][384]: q=p*384+0..127, k=+128, v=+256.
// attn flat [n][i*128+d] reinterpreted as [n][e][hw] by k_oproj (raw reshape).
// Column softmax (over i): scores s=q.k/64, |s|<~1.2 -> direct sum-exp (no max).
// R10: revert JH to 4 (512 blocks = 2/CU balanced single wave; R9's JH=8 tail cost 45%).
//      Keep 1/Z folded into Vt (no Ls). Add T14 async-STAGE: prefetch next K/V tile
//      into registers before compute so HBM/L2 latency hides under MFMA+exp phase.
//      Fix R9 k_oproj bug (nsl indexing read 4x the part data) -> back to unrolled s<4.

typedef short bfrag __attribute__((ext_vector_type(8)));   // 8 bf16 (4 VGPRs)
typedef float ffrag __attribute__((ext_vector_type(4)));   // 4 fp32 acc
typedef unsigned short us4 __attribute__((ext_vector_type(4)));
#define MFMA(a,b,c) __builtin_amdgcn_mfma_f32_16x16x32_bf16((a),(b),(c),0,0,0)

__device__ __forceinline__ unsigned short f2bf(float f){
  union { float f; unsigned u; } v; v.f = f;
  unsigned r = v.u + 0x7fffu + ((v.u >> 16) & 1u);   // RNE
  return (unsigned short)(r >> 16);
}
__device__ __forceinline__ float bf2f(unsigned short h){
  union { unsigned u; float f; } v; v.u = ((unsigned)h) << 16; return v.f;
}
__device__ __forceinline__ unsigned bfpack(float a, float b){
  return (unsigned)f2bf(a) | ((unsigned)f2bf(b) << 16);
}

// ---------------- K0: cast weights to bf16 ----------------
__global__ __launch_bounds__(256) void k_wcast(const float* __restrict__ Wq, const float* __restrict__ Wo,
                                               unsigned short* __restrict__ Wqb, unsigned short* __restrict__ Wob){
  int i = blockIdx.x*256 + threadIdx.x;
  if (i < 384*256) Wqb[i] = f2bf(Wq[i]);
  if (i < 256*128) Wob[i] = f2bf(Wo[i]);
}

// ---------------- K1: QKV projection, o-tile 128 (x re-read 3x instead of 6x) ----------------
__global__ __launch_bounds__(256) void k_qkv(const float* __restrict__ x, const unsigned short* __restrict__ Wqb,
                                             const float* __restrict__ bq, unsigned short* __restrict__ qkv){
  constexpr int LD = 136;
  __shared__ __align__(16) unsigned short As[128*LD];  // W tile [o 128][c-half 128]  34816 B
  __shared__ __align__(16) unsigned short Bs[64*LD];   // X^T tile [hw 64][c-half]    17408 B
  const int o0 = blockIdx.x*128, h0 = blockIdx.y*64, n = blockIdx.z;
  const int t = threadIdx.x, w = t>>6, lane = t&63, lr = lane&15, q4 = lane>>4;
  ffrag acc[8] = {};
  for (int kh = 0; kh < 2; ++kh) {
    __syncthreads();
    #pragma unroll
    for (int r=0;r<8;++r){                       // 2048 = 128 o x 16 segs
      int pi = t + 256*r; int o = pi>>4, seg = pi&15;
      *(uint4*)&As[o*LD + seg*8] = *(const uint4*)(Wqb + (o0+o)*256 + kh*128 + seg*8);
    }
    #pragma unroll
    for (int r=0;r<8;++r){                       // 2048 = 128 c x 16 h-quads, float4 loads
      int idx = t + 256*r; int cl = idx>>4, h4 = idx&15;
      float4 v = *(const float4*)(x + (size_t)(n*256 + kh*128 + cl)*4096 + h0 + h4*4);
      Bs[(h4*4+0)*LD + cl] = f2bf(v.x);
      Bs[(h4*4+1)*LD + cl] = f2bf(v.y);
      Bs[(h4*4+2)*LD + cl] = f2bf(v.z);
      Bs[(h4*4+3)*LD + cl] = f2bf(v.w);
    }
    __syncthreads();
    #pragma unroll
    for (int kk=0;kk<4;++kk){
      bfrag a = *(const bfrag*)&Bs[(w*16+lr)*LD + kk*32 + q4*8];   // A = x^T rows (hw)
      #pragma unroll
      for (int ot=0;ot<8;++ot){
        bfrag b = *(const bfrag*)&As[(ot*16+lr)*LD + kk*32 + q4*8]; // B = W rows (o)
        acc[ot] = MFMA(a,b,acc[ot]);                                // D[m=hw][n=o]
      }
    }
  }
  size_t base = (size_t)n*384*4096;
  #pragma unroll
  for (int ot=0;ot<8;++ot){
    int o  = o0 + ot*16 + lr;
    float bias = bq[o];
    int hw = h0 + w*16 + q4*4;
    us4 pk;
    pk.x = f2bf(acc[ot][0] + bias); pk.y = f2bf(acc[ot][1] + bias);
    pk.z = f2bf(acc[ot][2] + bias); pk.w = f2bf(acc[ot][3] + bias);
    *(us4*)(qkv + base + (size_t)o*4096 + hw) = pk;
  }
}

// ---------------- K2: column Z partials, wave owns 64 j (16 reg K-frags, 4 MFMA per Q read) ----------------
__global__ __launch_bounds__(256) void k_stats(const unsigned short* __restrict__ qkv,
                                               float* __restrict__ zp){
  constexpr int LD = 136;
  __shared__ __align__(16) unsigned short Qs[64*LD];   // 17408 B
  const int j0 = blockIdx.x*256, ic = blockIdx.y, n = blockIdx.z;
  const int t = threadIdx.x, w = t>>6, lane = t&63, lr = lane&15, q4 = lane>>4;
  size_t base = (size_t)n*384*4096;
  bfrag kf[4][4];
  #pragma unroll
  for (int js=0; js<4; ++js){
    const unsigned short* krow = qkv + base + (size_t)(j0 + w*64 + js*16 + lr)*384 + 128;
    #pragma unroll
    for (int kk=0;kk<4;++kk) kf[js][kk] = *(const bfrag*)(krow + kk*32 + q4*8);
  }
  float Zc[16] = {};                      // [js*4 + r]
  const float inv64 = 0.015625f;
  for (int rnd=0; rnd<8; ++rnd){          // 8 x 64-i stage rounds (ic chunk = 512 i)
    int i0 = (ic<<9) + rnd*64;
    __syncthreads();
    #pragma unroll
    for (int r=0;r<4;++r){
      int pi = t + 256*r; int il = pi>>4, seg = pi&15;
      *(uint4*)&Qs[il*LD + seg*8] = *(const uint4*)(qkv + base + (size_t)(i0+il)*384 + seg*8);
    }
    __syncthreads();
    #pragma unroll
    for (int it=0; it<4; ++it){
      bfrag qb[4];
      #pragma unroll
      for (int kk=0;kk<4;++kk) qb[kk] = *(const bfrag*)&Qs[(it*16+lr)*LD + kk*32 + q4*8];
      #pragma unroll
      for (int js=0; js<4; ++js){
        ffrag s = {};
        #pragma unroll
        for (int kk=0;kk<4;++kk) s = MFMA(kf[js][kk], qb[kk], s);   // D[m=j][n=i]
        #pragma unroll
        for (int r=0;r<4;++r) Zc[js*4+r] += __expf(s[r]*inv64);
      }
    }
  }
  #pragma unroll
  for (int v=0; v<16; ++v){
    float z = Zc[v];
    z += __shfl_xor(z, 1); z += __shfl_xor(z, 2);
    z += __shfl_xor(z, 4); z += __shfl_xor(z, 8);
    Zc[v] = z;
  }
  if (lr == 0){
    int jb = j0 + w*64;
    float* zrow = zp + (size_t)((n<<3)+ic)*4096;
    #pragma unroll
    for (int js=0; js<4; ++js)
      #pragma unroll
      for (int r=0;r<4;++r)
        zrow[jb + js*16 + q4*4 + r] = Zc[js*4+r];
  }
}

// ---------------- K3: V transpose + Z-merge + 1/Z fold: vt[n][d][p] = v[n][p][d] / Z[p] ----------------
__global__ __launch_bounds__(256) void k_vtrans(const unsigned short* __restrict__ qkv,
                                                const float* __restrict__ zp,
                                                unsigned short* __restrict__ vt){
  constexpr int LD = 136;
  __shared__ __align__(16) unsigned short T[64*LD];
  __shared__ float invZ[64];
  const int p0 = blockIdx.x*64, n = blockIdx.y;
  const int t = threadIdx.x;
  size_t base = (size_t)n*384*4096;
  #pragma unroll
  for (int r=0;r<4;++r){
    int pi = t + 256*r; int pl = pi>>4, seg = pi&15;
    *(uint4*)&T[pl*LD + seg*8] = *(const uint4*)(qkv + base + (size_t)(p0+pl)*384 + 256 + seg*8);
  }
  if (t < 64){                            // merge zp partials for this block's 64 j
    float Z = 0.f;
    #pragma unroll
    for (int c=0;c<8;++c) Z += zp[(size_t)((n<<3)+c)*4096 + p0 + t];
    invZ[t] = 1.0f / Z;
  }
  __syncthreads();
  unsigned* vt32 = (unsigned*)(vt + (size_t)n*128*4096);
  #pragma unroll
  for (int r=0;r<16;++r){
    int pi = t + 256*r;            // 4096 = 128 d x 32 p-pairs
    int d = pi>>5, k = pi&31;
    float lo = bf2f(T[(2*k)*LD + d])   * invZ[2*k];
    float hi = bf2f(T[(2*k+1)*LD + d]) * invZ[2*k+1];
    vt32[(size_t)d*2048 + (p0>>1) + k] = bfpack(lo, hi);
  }
}

// ---------------- K4: PV pass — T14 async-STAGE: prefetch next K/V tile into regs, ----------------
// ---------------- write to LDS after the barrier; load latency hides under compute ----------------
__global__ __launch_bounds__(256) void k_attn(const unsigned short* __restrict__ qkv,
                                              const unsigned short* __restrict__ vtg_all,
                                              unsigned short* __restrict__ part){
  constexpr int LDK = 136, LDV = 72, LDP = 72;
  __shared__ __align__(16) unsigned short Ks[64*LDK];    // 17408 B
  __shared__ __align__(16) unsigned short Vt[128*LDV];   // 18432 B
  __shared__ __align__(16) unsigned short Pw[4][32*LDP]; // 18432 B   total 54272 = 53 KiB
  const int i0 = blockIdx.x*128, jh = blockIdx.y, n = blockIdx.z;
  const int t = threadIdx.x, w = t>>6, lane = t&63, lr = lane&15, q4 = lane>>4;
  size_t base = (size_t)n*384*4096;
  const unsigned short* vtg = vtg_all + (size_t)n*128*4096;
  bfrag qf[2][4];   // B[k=d][n=i] for 2 i-subtiles (register-resident)
  #pragma unroll
  for (int isub=0;isub<2;++isub){
    const unsigned short* qrow = qkv + base + (size_t)(i0 + w*32 + isub*16 + lr)*384;
    #pragma unroll
    for (int kk=0;kk<4;++kk) qf[isub][kk] = *(const bfrag*)(qrow + kk*32 + q4*8);
  }
  ffrag acc[8][2] = {};
  const float inv64 = 0.015625f;

  // staging addresses (j0-invariant parts)
  const int jl_k = t>>4, seg_k = t&15;          // r-step adds 16 rows
  const int d_v  = t>>3, c_v  = t&7;            // r-step adds 32 d-rows
  uint4 kr[4], vr[4];
  int j0 = jh*1024;
  #pragma unroll
  for (int r=0;r<4;++r)
    kr[r] = *(const uint4*)(qkv + base + (size_t)(j0 + jl_k + 16*r)*384 + 128 + seg_k*8);
  #pragma unroll
  for (int r=0;r<4;++r)
    vr[r] = *(const uint4*)(vtg + (size_t)(d_v + 32*r)*4096 + j0 + c_v*8);

  for (int it=0; it<16; ++it, j0+=64){
    __syncthreads();                            // previous compute done reading LDS
    #pragma unroll
    for (int r=0;r<4;++r)
      *(uint4*)&Ks[(jl_k + 16*r)*LDK + seg_k*8] = kr[r];
    #pragma unroll
    for (int r=0;r<4;++r)
      *(uint4*)&Vt[(d_v + 32*r)*LDV + c_v*8] = vr[r];
    if (it < 15){                               // issue next tile's loads NOW;
      int jn = j0 + 64;                         // they complete during this tile's compute
      #pragma unroll
      for (int r=0;r<4;++r)
        kr[r] = *(const uint4*)(qkv + base + (size_t)(jn + jl_k + 16*r)*384 + 128 + seg_k*8);
      #pragma unroll
      for (int r=0;r<4;++r)
        vr[r] = *(const uint4*)(vtg + (size_t)(d_v + 32*r)*4096 + jn + c_v*8);
    }
    __syncthreads();                            // LDS tile ready
    #pragma unroll
    for (int jt=0;jt<4;++jt){
      bfrag kf[4];
      #pragma unroll
      for (int kk=0;kk<4;++kk) kf[kk] = *(const bfrag*)&Ks[(jt*16+lr)*LDK + kk*32 + q4*8]; // A[m=j][k=d]
      #pragma unroll
      for (int isub=0;isub<2;++isub){           // each K-frag feeds 2 MFMA chains
        ffrag s = {};
        #pragma unroll
        for (int kk=0;kk<4;++kk) s = MFMA(kf[kk], qf[isub][kk], s);   // D[m=j][n=i]
        float p0 = __expf(s[0]*inv64);
        float p1 = __expf(s[1]*inv64);
        float p2 = __expf(s[2]*inv64);
        float p3 = __expf(s[3]*inv64);
        uint2 pk; pk.x = bfpack(p0,p1); pk.y = bfpack(p2,p3);
        *(uint2*)&Pw[w][(isub*16+lr)*LDP + jt*16 + q4*4] = pk;   // wave-private
      }
    }
    asm volatile("" ::: "memory");              // no compiler reorder of Pw read above writes
    #pragma unroll
    for (int jk=0;jk<2;++jk){
      bfrag pf0 = *(const bfrag*)&Pw[w][lr*LDP      + jk*32 + q4*8];  // B[k=j][n=i] isub 0
      bfrag pf1 = *(const bfrag*)&Pw[w][(16+lr)*LDP + jk*32 + q4*8];  // isub 1
      #pragma unroll
      for (int dt=0;dt<8;++dt){
        bfrag af = *(const bfrag*)&Vt[(dt*16+lr)*LDV + jk*32 + q4*8]; // A[m=d][k=j], feeds 2 MFMAs
        acc[dt][0] = MFMA(af, pf0, acc[dt][0]);   // D[m=d][n=i]
        acc[dt][1] = MFMA(af, pf1, acc[dt][1]);
      }
    }
  }
  unsigned short* po = part + (size_t)(jh*4+n)*524288;
  #pragma unroll
  for (int isub=0;isub<2;++isub){
    const int i = i0 + w*32 + isub*16 + lr;
    #pragma unroll
    for (int dt=0;dt<8;++dt){
      us4 pk;
      pk.x = f2bf(acc[dt][isub][0]); pk.y = f2bf(acc[dt][isub][1]);
      pk.z = f2bf(acc[dt][isub][2]); pk.w = f2bf(acc[dt][isub][3]);
      *(us4*)(po + (size_t)i*128 + dt*16 + q4*4) = pk;
    }
  }
}

// ---------------- K5: output projection, sums 4 bf16 partial slices (uint4 loads), c-tile 128 ----------------
__global__ __launch_bounds__(256) void k_oproj(const unsigned short* __restrict__ part,
                                               const unsigned short* __restrict__ Wob,
                                               const float* __restrict__ bo, float* __restrict__ y){
  constexpr int LD = 136;
  __shared__ __align__(16) unsigned short As[128*LD];  // Wo tile [c][e]
  __shared__ __align__(16) unsigned short Rt[64*LD];   // attn^T [hw][e]
  const int c0 = blockIdx.x*128, h0 = blockIdx.y*64, n = blockIdx.z;
  const int t = threadIdx.x, w = t>>6, lane = t&63, lr = lane&15, q4 = lane>>4;
  #pragma unroll
  for (int r=0;r<8;++r){
    int pi = t + 256*r; int cl = pi>>4, seg = pi&15;
    *(uint4*)&As[cl*LD + seg*8] = *(const uint4*)(Wob + (c0+cl)*128 + seg*8);
  }
  #pragma unroll
  for (int r=0;r<4;++r){                     // 1024 = 128 e x 8 h-octets, uint4 loads
    int pi = t + 256*r; int e = pi>>3, h8 = pi&7;
    size_t f = (size_t)e*4096 + h0 + h8*8;
    float a[8] = {};
    #pragma unroll
    for (int s=0;s<4;++s){
      uint4 u = *(const uint4*)(part + (size_t)(s*4+n)*524288 + f);
      a[0] += bf2f((unsigned short)(u.x & 0xffffu)); a[1] += bf2f((unsigned short)(u.x >> 16));
      a[2] += bf2f((unsigned short)(u.y & 0xffffu)); a[3] += bf2f((unsigned short)(u.y >> 16));
      a[4] += bf2f((unsigned short)(u.z & 0xffffu)); a[5] += bf2f((unsigned short)(u.z >> 16));
      a[6] += bf2f((unsigned short)(u.w & 0xffffu)); a[7] += bf2f((unsigned short)(u.w >> 16));
    }
    #pragma unroll
    for (int k=0;k<8;++k) Rt[(h8*8+k)*LD + e] = f2bf(a[k]);
  }
  __syncthreads();
  ffrag acc[8] = {};
  #pragma unroll
  for (int kk=0;kk<4;++kk){
    bfrag a = *(const bfrag*)&Rt[(w*16+lr)*LD + kk*32 + q4*8];   // A = attn^T rows (hw)
    #pragma unroll
    for (int cs=0;cs<8;++cs){
      bfrag b = *(const bfrag*)&As[(cs*16+lr)*LD + kk*32 + q4*8]; // B = Wo rows (c)
      acc[cs] = MFMA(a,b,acc[cs]);                                // D[m=hw][n=c]
    }
  }
  #pragma unroll
  for (int cs=0;cs<8;++cs){
    int c = c0 + cs*16 + lr;
    float bias = bo[c];
    float4 v4 = { acc[cs][0]+bias, acc[cs][1]+bias, acc[cs][2]+bias, acc[cs][3]+bias };
    *(float4*)(y + ((size_t)n*256 + c)*4096 + h0 + w*16 + q4*4) = v4;
  }
}

extern "C" void kernel_launch(void* const* d_in, const int* in_sizes, int n_in,
                              void* d_out, int out_size, void* d_ws, size_t ws_size,
                              hipStream_t stream){
  const float* x  = (const float*)d_in[0];
  const float* Wq = (const float*)d_in[1];
  const float* bq = (const float*)d_in[2];
  const float* Wo = (const float*)d_in[3];
  const float* bo = (const float*)d_in[4];
  float* y = (float*)d_out;
  char* ws = (char*)d_ws;
  unsigned short* qkv  = (unsigned short*)(ws + 0);          // 12,582,912
  unsigned short* vtg  = (unsigned short*)(ws + 12582912);   //  4,194,304
  unsigned short* Wqb  = (unsigned short*)(ws + 16777216);   //    196,608
  unsigned short* Wob  = (unsigned short*)(ws + 16973824);   //     65,536
  float* zp   = (float*)(ws + 17039360);                     //    524,288 (4n x 8ic x 4096)
  unsigned short* part = (unsigned short*)(ws + 17629184);   // 16,777,216 (16 bf16 slices jh*4+n) end ~34.4MB

  k_wcast <<<dim3(384),     256, 0, stream>>>(Wq, Wo, Wqb, Wob);
  k_qkv   <<<dim3(3,64,4),  256, 0, stream>>>(x, Wqb, bq, qkv);
  k_stats <<<dim3(16,8,4),  256, 0, stream>>>(qkv, zp);
  k_vtrans<<<dim3(64,4),    256, 0, stream>>>(qkv, zp, vtg);
  k_attn  <<<dim3(32,4,4),  256, 0, stream>>>(qkv, vtg, part);
  k_oproj <<<dim3(2,64,4),  256, 0, stream>>>(part, Wob, bo, y);
}

// Round 3
// 229.382 us; speedup vs baseline: 1.0772x; 1.0712x over previous
//
#include <hip/hip_runtime.h>
#include <hip/hip_bf16.h>

// N=4, C=256, H=W=64 -> HW=4096, E=128, 3E=384.
// qkv flat [n][o][hw] IS [n][p][384]: q=p*384+0..127, k=+128, v=+256.
// attn flat [n][i*128+d] reinterpreted as [n][e][hw] by k_oproj (raw reshape).
// Column softmax (over i): scores s=q.k/64, |s|<~1.2 -> direct sum-exp (no max).
// R11: no reg-prefetch (R10 spilled: WRITE 16->220MB). no-Ls inner (53 KiB LDS ->
//      3 blocks/CU). Grid (32,6,4)=768 = EXACTLY 3x256 CUs resident, no tail
//      (R9's 1024-block JH=8 had a 256-block straggler phase at 1 blk/CU).
//      j-chunks via floor(jh*64/6) tile bounds: sizes 10,11,11,10,11,11.
//      k_oproj sums 6 slices, unrolled, slice index s*4+n (R9 bug fixed in R10).

typedef short bfrag __attribute__((ext_vector_type(8)));   // 8 bf16 (4 VGPRs)
typedef float ffrag __attribute__((ext_vector_type(4)));   // 4 fp32 acc
typedef unsigned short us4 __attribute__((ext_vector_type(4)));
#define MFMA(a,b,c) __builtin_amdgcn_mfma_f32_16x16x32_bf16((a),(b),(c),0,0,0)

__device__ __forceinline__ unsigned short f2bf(float f){
  union { float f; unsigned u; } v; v.f = f;
  unsigned r = v.u + 0x7fffu + ((v.u >> 16) & 1u);   // RNE
  return (unsigned short)(r >> 16);
}
__device__ __forceinline__ float bf2f(unsigned short h){
  union { unsigned u; float f; } v; v.u = ((unsigned)h) << 16; return v.f;
}
__device__ __forceinline__ unsigned bfpack(float a, float b){
  return (unsigned)f2bf(a) | ((unsigned)f2bf(b) << 16);
}

// ---------------- K0: cast weights to bf16 ----------------
__global__ __launch_bounds__(256) void k_wcast(const float* __restrict__ Wq, const float* __restrict__ Wo,
                                               unsigned short* __restrict__ Wqb, unsigned short* __restrict__ Wob){
  int i = blockIdx.x*256 + threadIdx.x;
  if (i < 384*256) Wqb[i] = f2bf(Wq[i]);
  if (i < 256*128) Wob[i] = f2bf(Wo[i]);
}

// ---------------- K1: QKV projection, o-tile 128 (x re-read 3x instead of 6x) ----------------
__global__ __launch_bounds__(256) void k_qkv(const float* __restrict__ x, const unsigned short* __restrict__ Wqb,
                                             const float* __restrict__ bq, unsigned short* __restrict__ qkv){
  constexpr int LD = 136;
  __shared__ __align__(16) unsigned short As[128*LD];  // W tile [o 128][c-half 128]  34816 B
  __shared__ __align__(16) unsigned short Bs[64*LD];   // X^T tile [hw 64][c-half]    17408 B
  const int o0 = blockIdx.x*128, h0 = blockIdx.y*64, n = blockIdx.z;
  const int t = threadIdx.x, w = t>>6, lane = t&63, lr = lane&15, q4 = lane>>4;
  ffrag acc[8] = {};
  for (int kh = 0; kh < 2; ++kh) {
    __syncthreads();
    #pragma unroll
    for (int r=0;r<8;++r){                       // 2048 = 128 o x 16 segs
      int pi = t + 256*r; int o = pi>>4, seg = pi&15;
      *(uint4*)&As[o*LD + seg*8] = *(const uint4*)(Wqb + (o0+o)*256 + kh*128 + seg*8);
    }
    #pragma unroll
    for (int r=0;r<8;++r){                       // 2048 = 128 c x 16 h-quads, float4 loads
      int idx = t + 256*r; int cl = idx>>4, h4 = idx&15;
      float4 v = *(const float4*)(x + (size_t)(n*256 + kh*128 + cl)*4096 + h0 + h4*4);
      Bs[(h4*4+0)*LD + cl] = f2bf(v.x);
      Bs[(h4*4+1)*LD + cl] = f2bf(v.y);
      Bs[(h4*4+2)*LD + cl] = f2bf(v.z);
      Bs[(h4*4+3)*LD + cl] = f2bf(v.w);
    }
    __syncthreads();
    #pragma unroll
    for (int kk=0;kk<4;++kk){
      bfrag a = *(const bfrag*)&Bs[(w*16+lr)*LD + kk*32 + q4*8];   // A = x^T rows (hw)
      #pragma unroll
      for (int ot=0;ot<8;++ot){
        bfrag b = *(const bfrag*)&As[(ot*16+lr)*LD + kk*32 + q4*8]; // B = W rows (o)
        acc[ot] = MFMA(a,b,acc[ot]);                                // D[m=hw][n=o]
      }
    }
  }
  size_t base = (size_t)n*384*4096;
  #pragma unroll
  for (int ot=0;ot<8;++ot){
    int o  = o0 + ot*16 + lr;
    float bias = bq[o];
    int hw = h0 + w*16 + q4*4;
    us4 pk;
    pk.x = f2bf(acc[ot][0] + bias); pk.y = f2bf(acc[ot][1] + bias);
    pk.z = f2bf(acc[ot][2] + bias); pk.w = f2bf(acc[ot][3] + bias);
    *(us4*)(qkv + base + (size_t)o*4096 + hw) = pk;
  }
}

// ---------------- K2: column Z partials, wave owns 64 j (16 reg K-frags, 4 MFMA per Q read) ----------------
__global__ __launch_bounds__(256) void k_stats(const unsigned short* __restrict__ qkv,
                                               float* __restrict__ zp){
  constexpr int LD = 136;
  __shared__ __align__(16) unsigned short Qs[64*LD];   // 17408 B
  const int j0 = blockIdx.x*256, ic = blockIdx.y, n = blockIdx.z;
  const int t = threadIdx.x, w = t>>6, lane = t&63, lr = lane&15, q4 = lane>>4;
  size_t base = (size_t)n*384*4096;
  bfrag kf[4][4];
  #pragma unroll
  for (int js=0; js<4; ++js){
    const unsigned short* krow = qkv + base + (size_t)(j0 + w*64 + js*16 + lr)*384 + 128;
    #pragma unroll
    for (int kk=0;kk<4;++kk) kf[js][kk] = *(const bfrag*)(krow + kk*32 + q4*8);
  }
  float Zc[16] = {};                      // [js*4 + r]
  const float inv64 = 0.015625f;
  for (int rnd=0; rnd<8; ++rnd){          // 8 x 64-i stage rounds (ic chunk = 512 i)
    int i0 = (ic<<9) + rnd*64;
    __syncthreads();
    #pragma unroll
    for (int r=0;r<4;++r){
      int pi = t + 256*r; int il = pi>>4, seg = pi&15;
      *(uint4*)&Qs[il*LD + seg*8] = *(const uint4*)(qkv + base + (size_t)(i0+il)*384 + seg*8);
    }
    __syncthreads();
    #pragma unroll
    for (int it=0; it<4; ++it){
      bfrag qb[4];
      #pragma unroll
      for (int kk=0;kk<4;++kk) qb[kk] = *(const bfrag*)&Qs[(it*16+lr)*LD + kk*32 + q4*8];
      #pragma unroll
      for (int js=0; js<4; ++js){
        ffrag s = {};
        #pragma unroll
        for (int kk=0;kk<4;++kk) s = MFMA(kf[js][kk], qb[kk], s);   // D[m=j][n=i]
        #pragma unroll
        for (int r=0;r<4;++r) Zc[js*4+r] += __expf(s[r]*inv64);
      }
    }
  }
  #pragma unroll
  for (int v=0; v<16; ++v){
    float z = Zc[v];
    z += __shfl_xor(z, 1); z += __shfl_xor(z, 2);
    z += __shfl_xor(z, 4); z += __shfl_xor(z, 8);
    Zc[v] = z;
  }
  if (lr == 0){
    int jb = j0 + w*64;
    float* zrow = zp + (size_t)((n<<3)+ic)*4096;
    #pragma unroll
    for (int js=0; js<4; ++js)
      #pragma unroll
      for (int r=0;r<4;++r)
        zrow[jb + js*16 + q4*4 + r] = Zc[js*4+r];
  }
}

// ---------------- K3: V transpose + Z-merge + 1/Z fold: vt[n][d][p] = v[n][p][d] / Z[p] ----------------
__global__ __launch_bounds__(256) void k_vtrans(const unsigned short* __restrict__ qkv,
                                                const float* __restrict__ zp,
                                                unsigned short* __restrict__ vt){
  constexpr int LD = 136;
  __shared__ __align__(16) unsigned short T[64*LD];
  __shared__ float invZ[64];
  const int p0 = blockIdx.x*64, n = blockIdx.y;
  const int t = threadIdx.x;
  size_t base = (size_t)n*384*4096;
  #pragma unroll
  for (int r=0;r<4;++r){
    int pi = t + 256*r; int pl = pi>>4, seg = pi&15;
    *(uint4*)&T[pl*LD + seg*8] = *(const uint4*)(qkv + base + (size_t)(p0+pl)*384 + 256 + seg*8);
  }
  if (t < 64){                            // merge zp partials for this block's 64 j
    float Z = 0.f;
    #pragma unroll
    for (int c=0;c<8;++c) Z += zp[(size_t)((n<<3)+c)*4096 + p0 + t];
    invZ[t] = 1.0f / Z;
  }
  __syncthreads();
  unsigned* vt32 = (unsigned*)(vt + (size_t)n*128*4096);
  #pragma unroll
  for (int r=0;r<16;++r){
    int pi = t + 256*r;            // 4096 = 128 d x 32 p-pairs
    int d = pi>>5, k = pi&31;
    float lo = bf2f(T[(2*k)*LD + d])   * invZ[2*k];
    float hi = bf2f(T[(2*k+1)*LD + d]) * invZ[2*k+1];
    vt32[(size_t)d*2048 + (p0>>1) + k] = bfpack(lo, hi);
  }
}

// ---------------- K4: PV pass — no-Ls (53 KiB LDS, 3 blk/CU), grid exactly 768 = 3x256 ----------------
__global__ __launch_bounds__(256) void k_attn(const unsigned short* __restrict__ qkv,
                                              const unsigned short* __restrict__ vtg_all,
                                              unsigned short* __restrict__ part){
  constexpr int LDK = 136, LDV = 72, LDP = 72;
  __shared__ __align__(16) unsigned short Ks[64*LDK];    // 17408 B
  __shared__ __align__(16) unsigned short Vt[128*LDV];   // 18432 B
  __shared__ __align__(16) unsigned short Pw[4][32*LDP]; // 18432 B   total 54272 = 53 KiB
  const int i0 = blockIdx.x*128, jh = blockIdx.y, n = blockIdx.z;
  const int t = threadIdx.x, w = t>>6, lane = t&63, lr = lane&15, q4 = lane>>4;
  size_t base = (size_t)n*384*4096;
  const unsigned short* vtg = vtg_all + (size_t)n*128*4096;
  bfrag qf[2][4];   // B[k=d][n=i] for 2 i-subtiles (register-resident)
  #pragma unroll
  for (int isub=0;isub<2;++isub){
    const unsigned short* qrow = qkv + base + (size_t)(i0 + w*32 + isub*16 + lr)*384;
    #pragma unroll
    for (int kk=0;kk<4;++kk) qf[isub][kk] = *(const bfrag*)(qrow + kk*32 + q4*8);
  }
  ffrag acc[8][2] = {};
  const float inv64 = 0.015625f;
  // j-tile bounds: chunk jh covers tiles [jh*64/6, (jh+1)*64/6) of 64 total
  const int t0 = (jh*64)/6, t1 = ((jh+1)*64)/6;
  for (int tile = t0; tile < t1; ++tile){
    const int j0 = tile*64;
    __syncthreads();
    #pragma unroll
    for (int r=0;r<4;++r){                    // K rows j0..j0+63
      int pi = t + 256*r; int jl = pi>>4, seg = pi&15;
      *(uint4*)&Ks[jl*LDK + seg*8] = *(const uint4*)(qkv + base + (size_t)(j0+jl)*384 + 128 + seg*8);
    }
    #pragma unroll
    for (int r=0;r<4;++r){                    // Vt[128 d][64 j] (pre-scaled by 1/Z[j])
      int pi = t + 256*r; int d = pi>>3, c = pi&7;
      *(uint4*)&Vt[d*LDV + c*8] = *(const uint4*)(vtg + (size_t)d*4096 + j0 + c*8);
    }
    __syncthreads();
    #pragma unroll
    for (int jt=0;jt<4;++jt){
      bfrag kf[4];
      #pragma unroll
      for (int kk=0;kk<4;++kk) kf[kk] = *(const bfrag*)&Ks[(jt*16+lr)*LDK + kk*32 + q4*8]; // A[m=j][k=d]
      #pragma unroll
      for (int isub=0;isub<2;++isub){         // each K-frag feeds 2 MFMA chains
        ffrag s = {};
        #pragma unroll
        for (int kk=0;kk<4;++kk) s = MFMA(kf[kk], qf[isub][kk], s);   // D[m=j][n=i]
        float p0 = __expf(s[0]*inv64);
        float p1 = __expf(s[1]*inv64);
        float p2 = __expf(s[2]*inv64);
        float p3 = __expf(s[3]*inv64);
        uint2 pk; pk.x = bfpack(p0,p1); pk.y = bfpack(p2,p3);
        *(uint2*)&Pw[w][(isub*16+lr)*LDP + jt*16 + q4*4] = pk;   // wave-private
      }
    }
    asm volatile("" ::: "memory");             // no compiler reorder of Pw read above writes
    #pragma unroll
    for (int jk=0;jk<2;++jk){
      bfrag pf0 = *(const bfrag*)&Pw[w][lr*LDP      + jk*32 + q4*8];  // B[k=j][n=i] isub 0
      bfrag pf1 = *(const bfrag*)&Pw[w][(16+lr)*LDP + jk*32 + q4*8];  // isub 1
      #pragma unroll
      for (int dt=0;dt<8;++dt){
        bfrag af = *(const bfrag*)&Vt[(dt*16+lr)*LDV + jk*32 + q4*8]; // A[m=d][k=j], feeds 2 MFMAs
        acc[dt][0] = MFMA(af, pf0, acc[dt][0]);   // D[m=d][n=i]
        acc[dt][1] = MFMA(af, pf1, acc[dt][1]);
      }
    }
  }
  unsigned short* po = part + (size_t)(jh*4+n)*524288;
  #pragma unroll
  for (int isub=0;isub<2;++isub){
    const int i = i0 + w*32 + isub*16 + lr;
    #pragma unroll
    for (int dt=0;dt<8;++dt){
      us4 pk;
      pk.x = f2bf(acc[dt][isub][0]); pk.y = f2bf(acc[dt][isub][1]);
      pk.z = f2bf(acc[dt][isub][2]); pk.w = f2bf(acc[dt][isub][3]);
      *(us4*)(po + (size_t)i*128 + dt*16 + q4*4) = pk;
    }
  }
}

// ---------------- K5: output projection, sums 6 bf16 partial slices (uint4 loads), c-tile 128 ----------------
__global__ __launch_bounds__(256) void k_oproj(const unsigned short* __restrict__ part,
                                               const unsigned short* __restrict__ Wob,
                                               const float* __restrict__ bo, float* __restrict__ y){
  constexpr int LD = 136;
  __shared__ __align__(16) unsigned short As[128*LD];  // Wo tile [c][e]
  __shared__ __align__(16) unsigned short Rt[64*LD];   // attn^T [hw][e]
  const int c0 = blockIdx.x*128, h0 = blockIdx.y*64, n = blockIdx.z;
  const int t = threadIdx.x, w = t>>6, lane = t&63, lr = lane&15, q4 = lane>>4;
  #pragma unroll
  for (int r=0;r<8;++r){
    int pi = t + 256*r; int cl = pi>>4, seg = pi&15;
    *(uint4*)&As[cl*LD + seg*8] = *(const uint4*)(Wob + (c0+cl)*128 + seg*8);
  }
  #pragma unroll
  for (int r=0;r<4;++r){                     // 1024 = 128 e x 8 h-octets, uint4 loads
    int pi = t + 256*r; int e = pi>>3, h8 = pi&7;
    size_t f = (size_t)e*4096 + h0 + h8*8;
    float a[8] = {};
    #pragma unroll
    for (int s=0;s<6;++s){                   // 6 j-chunk slices, layout (s*4+n)
      uint4 u = *(const uint4*)(part + (size_t)(s*4+n)*524288 + f);
      a[0] += bf2f((unsigned short)(u.x & 0xffffu)); a[1] += bf2f((unsigned short)(u.x >> 16));
      a[2] += bf2f((unsigned short)(u.y & 0xffffu)); a[3] += bf2f((unsigned short)(u.y >> 16));
      a[4] += bf2f((unsigned short)(u.z & 0xffffu)); a[5] += bf2f((unsigned short)(u.z >> 16));
      a[6] += bf2f((unsigned short)(u.w & 0xffffu)); a[7] += bf2f((unsigned short)(u.w >> 16));
    }
    #pragma unroll
    for (int k=0;k<8;++k) Rt[(h8*8+k)*LD + e] = f2bf(a[k]);
  }
  __syncthreads();
  ffrag acc[8] = {};
  #pragma unroll
  for (int kk=0;kk<4;++kk){
    bfrag a = *(const bfrag*)&Rt[(w*16+lr)*LD + kk*32 + q4*8];   // A = attn^T rows (hw)
    #pragma unroll
    for (int cs=0;cs<8;++cs){
      bfrag b = *(const bfrag*)&As[(cs*16+lr)*LD + kk*32 + q4*8]; // B = Wo rows (c)
      acc[cs] = MFMA(a,b,acc[cs]);                                // D[m=hw][n=c]
    }
  }
  #pragma unroll
  for (int cs=0;cs<8;++cs){
    int c = c0 + cs*16 + lr;
    float bias = bo[c];
    float4 v4 = { acc[cs][0]+bias, acc[cs][1]+bias, acc[cs][2]+bias, acc[cs][3]+bias };
    *(float4*)(y + ((size_t)n*256 + c)*4096 + h0 + w*16 + q4*4) = v4;
  }
}

extern "C" void kernel_launch(void* const* d_in, const int* in_sizes, int n_in,
                              void* d_out, int out_size, void* d_ws, size_t ws_size,
                              hipStream_t stream){
  const float* x  = (const float*)d_in[0];
  const float* Wq = (const float*)d_in[1];
  const float* bq = (const float*)d_in[2];
  const float* Wo = (const float*)d_in[3];
  const float* bo = (const float*)d_in[4];
  float* y = (float*)d_out;
  char* ws = (char*)d_ws;
  unsigned short* qkv  = (unsigned short*)(ws + 0);          // 12,582,912
  unsigned short* vtg  = (unsigned short*)(ws + 12582912);   //  4,194,304
  unsigned short* Wqb  = (unsigned short*)(ws + 16777216);   //    196,608
  unsigned short* Wob  = (unsigned short*)(ws + 16973824);   //     65,536
  float* zp   = (float*)(ws + 17039360);                     //    524,288 (4n x 8ic x 4096)
  unsigned short* part = (unsigned short*)(ws + 17629184);   // 24 slices x 1 MiB (jh*4+n), end ~41.6MB

  k_wcast <<<dim3(384),     256, 0, stream>>>(Wq, Wo, Wqb, Wob);
  k_qkv   <<<dim3(3,64,4),  256, 0, stream>>>(x, Wqb, bq, qkv);
  k_stats <<<dim3(16,8,4),  256, 0, stream>>>(qkv, zp);
  k_vtrans<<<dim3(64,4),    256, 0, stream>>>(qkv, zp, vtg);
  k_attn  <<<dim3(32,6,4),  256, 0, stream>>>(qkv, vtg, part);
  k_oproj <<<dim3(2,64,4),  256, 0, stream>>>(part, Wob, bo, y);
}

// Round 4
// 179.909 us; speedup vs baseline: 1.3734x; 1.2750x over previous
//
#include <hip/hip_runtime.h>
#include <hip/hip_bf16.h>

// N=4, C=256, H=W=64 -> HW=4096, E=128, 3E=384.
// qkv flat [n][o][hw] IS [n][p][384]: q=p*384+0..127, k=+128, v=+256.
// attn flat [n][i*128+d] reinterpreted as [n][e][hw] by k_oproj (raw reshape).
// Column softmax (over i): scores s=q.k/64, |s|<~1.2 -> direct sum-exp (no max).
// R12: grid back to (32,4,4)=512=2/CU exact (R1/R3: capacity is effectively 2; 3 never
//      materialized). k_attn restructured:
//      (a) Pw LDS buffer removed -> P redistributed via 32 __shfl + selects per tile
//          (D rows q4*4+r -> B rows q4*8+e; srcLane = lr+16*((2q4+(m>>1))&3),
//           jt-half = 2jk+(q4>>1) selected by q4>=2).
//      (b) Ks/Vt double-buffered (71,680 B, still 2 blk/CU): next-tile global loads
//          issued before compute, ds_writes sunk after, ONE barrier/iter.
//      (c) __launch_bounds__(256,2) so staged regs get VGPRs instead of spilling
//          (R2's 220MB WRITE_SIZE = spill at the default 80-VGPR budget).

typedef short bfrag __attribute__((ext_vector_type(8)));   // 8 bf16 (4 VGPRs)
typedef float ffrag __attribute__((ext_vector_type(4)));   // 4 fp32 acc
typedef unsigned short us4 __attribute__((ext_vector_type(4)));
#define MFMA(a,b,c) __builtin_amdgcn_mfma_f32_16x16x32_bf16((a),(b),(c),0,0,0)

__device__ __forceinline__ unsigned short f2bf(float f){
  union { float f; unsigned u; } v; v.f = f;
  unsigned r = v.u + 0x7fffu + ((v.u >> 16) & 1u);   // RNE
  return (unsigned short)(r >> 16);
}
__device__ __forceinline__ float bf2f(unsigned short h){
  union { unsigned u; float f; } v; v.u = ((unsigned)h) << 16; return v.f;
}
__device__ __forceinline__ unsigned bfpack(float a, float b){
  return (unsigned)f2bf(a) | ((unsigned)f2bf(b) << 16);
}

// ---------------- K0: cast weights to bf16 ----------------
__global__ __launch_bounds__(256) void k_wcast(const float* __restrict__ Wq, const float* __restrict__ Wo,
                                               unsigned short* __restrict__ Wqb, unsigned short* __restrict__ Wob){
  int i = blockIdx.x*256 + threadIdx.x;
  if (i < 384*256) Wqb[i] = f2bf(Wq[i]);
  if (i < 256*128) Wob[i] = f2bf(Wo[i]);
}

// ---------------- K1: QKV projection, o-tile 128 (x re-read 3x instead of 6x) ----------------
__global__ __launch_bounds__(256) void k_qkv(const float* __restrict__ x, const unsigned short* __restrict__ Wqb,
                                             const float* __restrict__ bq, unsigned short* __restrict__ qkv){
  constexpr int LD = 136;
  __shared__ __align__(16) unsigned short As[128*LD];  // W tile [o 128][c-half 128]  34816 B
  __shared__ __align__(16) unsigned short Bs[64*LD];   // X^T tile [hw 64][c-half]    17408 B
  const int o0 = blockIdx.x*128, h0 = blockIdx.y*64, n = blockIdx.z;
  const int t = threadIdx.x, w = t>>6, lane = t&63, lr = lane&15, q4 = lane>>4;
  ffrag acc[8] = {};
  for (int kh = 0; kh < 2; ++kh) {
    __syncthreads();
    #pragma unroll
    for (int r=0;r<8;++r){                       // 2048 = 128 o x 16 segs
      int pi = t + 256*r; int o = pi>>4, seg = pi&15;
      *(uint4*)&As[o*LD + seg*8] = *(const uint4*)(Wqb + (o0+o)*256 + kh*128 + seg*8);
    }
    #pragma unroll
    for (int r=0;r<8;++r){                       // 2048 = 128 c x 16 h-quads, float4 loads
      int idx = t + 256*r; int cl = idx>>4, h4 = idx&15;
      float4 v = *(const float4*)(x + (size_t)(n*256 + kh*128 + cl)*4096 + h0 + h4*4);
      Bs[(h4*4+0)*LD + cl] = f2bf(v.x);
      Bs[(h4*4+1)*LD + cl] = f2bf(v.y);
      Bs[(h4*4+2)*LD + cl] = f2bf(v.z);
      Bs[(h4*4+3)*LD + cl] = f2bf(v.w);
    }
    __syncthreads();
    #pragma unroll
    for (int kk=0;kk<4;++kk){
      bfrag a = *(const bfrag*)&Bs[(w*16+lr)*LD + kk*32 + q4*8];   // A = x^T rows (hw)
      #pragma unroll
      for (int ot=0;ot<8;++ot){
        bfrag b = *(const bfrag*)&As[(ot*16+lr)*LD + kk*32 + q4*8]; // B = W rows (o)
        acc[ot] = MFMA(a,b,acc[ot]);                                // D[m=hw][n=o]
      }
    }
  }
  size_t base = (size_t)n*384*4096;
  #pragma unroll
  for (int ot=0;ot<8;++ot){
    int o  = o0 + ot*16 + lr;
    float bias = bq[o];
    int hw = h0 + w*16 + q4*4;
    us4 pk;
    pk.x = f2bf(acc[ot][0] + bias); pk.y = f2bf(acc[ot][1] + bias);
    pk.z = f2bf(acc[ot][2] + bias); pk.w = f2bf(acc[ot][3] + bias);
    *(us4*)(qkv + base + (size_t)o*4096 + hw) = pk;
  }
}

// ---------------- K2: column Z partials, wave owns 64 j (16 reg K-frags, 4 MFMA per Q read) ----------------
__global__ __launch_bounds__(256) void k_stats(const unsigned short* __restrict__ qkv,
                                               float* __restrict__ zp){
  constexpr int LD = 136;
  __shared__ __align__(16) unsigned short Qs[64*LD];   // 17408 B
  const int j0 = blockIdx.x*256, ic = blockIdx.y, n = blockIdx.z;
  const int t = threadIdx.x, w = t>>6, lane = t&63, lr = lane&15, q4 = lane>>4;
  size_t base = (size_t)n*384*4096;
  bfrag kf[4][4];
  #pragma unroll
  for (int js=0; js<4; ++js){
    const unsigned short* krow = qkv + base + (size_t)(j0 + w*64 + js*16 + lr)*384 + 128;
    #pragma unroll
    for (int kk=0;kk<4;++kk) kf[js][kk] = *(const bfrag*)(krow + kk*32 + q4*8);
  }
  float Zc[16] = {};                      // [js*4 + r]
  const float inv64 = 0.015625f;
  for (int rnd=0; rnd<8; ++rnd){          // 8 x 64-i stage rounds (ic chunk = 512 i)
    int i0 = (ic<<9) + rnd*64;
    __syncthreads();
    #pragma unroll
    for (int r=0;r<4;++r){
      int pi = t + 256*r; int il = pi>>4, seg = pi&15;
      *(uint4*)&Qs[il*LD + seg*8] = *(const uint4*)(qkv + base + (size_t)(i0+il)*384 + seg*8);
    }
    __syncthreads();
    #pragma unroll
    for (int it=0; it<4; ++it){
      bfrag qb[4];
      #pragma unroll
      for (int kk=0;kk<4;++kk) qb[kk] = *(const bfrag*)&Qs[(it*16+lr)*LD + kk*32 + q4*8];
      #pragma unroll
      for (int js=0; js<4; ++js){
        ffrag s = {};
        #pragma unroll
        for (int kk=0;kk<4;++kk) s = MFMA(kf[js][kk], qb[kk], s);   // D[m=j][n=i]
        #pragma unroll
        for (int r=0;r<4;++r) Zc[js*4+r] += __expf(s[r]*inv64);
      }
    }
  }
  #pragma unroll
  for (int v=0; v<16; ++v){
    float z = Zc[v];
    z += __shfl_xor(z, 1); z += __shfl_xor(z, 2);
    z += __shfl_xor(z, 4); z += __shfl_xor(z, 8);
    Zc[v] = z;
  }
  if (lr == 0){
    int jb = j0 + w*64;
    float* zrow = zp + (size_t)((n<<3)+ic)*4096;
    #pragma unroll
    for (int js=0; js<4; ++js)
      #pragma unroll
      for (int r=0;r<4;++r)
        zrow[jb + js*16 + q4*4 + r] = Zc[js*4+r];
  }
}

// ---------------- K3: V transpose + Z-merge + 1/Z fold: vt[n][d][p] = v[n][p][d] / Z[p] ----------------
__global__ __launch_bounds__(256) void k_vtrans(const unsigned short* __restrict__ qkv,
                                                const float* __restrict__ zp,
                                                unsigned short* __restrict__ vt){
  constexpr int LD = 136;
  __shared__ __align__(16) unsigned short T[64*LD];
  __shared__ float invZ[64];
  const int p0 = blockIdx.x*64, n = blockIdx.y;
  const int t = threadIdx.x;
  size_t base = (size_t)n*384*4096;
  #pragma unroll
  for (int r=0;r<4;++r){
    int pi = t + 256*r; int pl = pi>>4, seg = pi&15;
    *(uint4*)&T[pl*LD + seg*8] = *(const uint4*)(qkv + base + (size_t)(p0+pl)*384 + 256 + seg*8);
  }
  if (t < 64){                            // merge zp partials for this block's 64 j
    float Z = 0.f;
    #pragma unroll
    for (int c=0;c<8;++c) Z += zp[(size_t)((n<<3)+c)*4096 + p0 + t];
    invZ[t] = 1.0f / Z;
  }
  __syncthreads();
  unsigned* vt32 = (unsigned*)(vt + (size_t)n*128*4096);
  #pragma unroll
  for (int r=0;r<16;++r){
    int pi = t + 256*r;            // 4096 = 128 d x 32 p-pairs
    int d = pi>>5, k = pi&31;
    float lo = bf2f(T[(2*k)*LD + d])   * invZ[2*k];
    float hi = bf2f(T[(2*k+1)*LD + d]) * invZ[2*k+1];
    vt32[(size_t)d*2048 + (p0>>1) + k] = bfpack(lo, hi);
  }
}

// ---------------- K4: PV pass — no Pw (shuffle P redistribution), dbuf Ks/Vt, 1 barrier/iter ----------------
__global__ __launch_bounds__(256, 2) void k_attn(const unsigned short* __restrict__ qkv,
                                                 const unsigned short* __restrict__ vtg_all,
                                                 unsigned short* __restrict__ part){
  constexpr int LDK = 136, LDV = 72;
  __shared__ __align__(16) unsigned short Ks[2][64*LDK];    // 2 x 17408 B
  __shared__ __align__(16) unsigned short Vt[2][128*LDV];   // 2 x 18432 B   total 71680
  const int i0 = blockIdx.x*128, jh = blockIdx.y, n = blockIdx.z;
  const int t = threadIdx.x, w = t>>6, lane = t&63, lr = lane&15, q4 = lane>>4;
  size_t base = (size_t)n*384*4096;
  const unsigned short* vtg = vtg_all + (size_t)n*128*4096;
  bfrag qf[2][4];   // B[k=d][n=i] for 2 i-subtiles (register-resident)
  #pragma unroll
  for (int isub=0;isub<2;++isub){
    const unsigned short* qrow = qkv + base + (size_t)(i0 + w*32 + isub*16 + lr)*384;
    #pragma unroll
    for (int kk=0;kk<4;++kk) qf[isub][kk] = *(const bfrag*)(qrow + kk*32 + q4*8);
  }
  ffrag acc[8][2] = {};
  const float inv64 = 0.015625f;

  // staging addressing (tile-invariant parts)
  const int jl_k = t>>4, seg_k = t&15;          // K: 16 rows per r-step
  const int d_v  = t>>3, c_v  = t&7;            // V: 32 d-rows per r-step
  // shuffle source lanes: q4' = (2q4 + (m>>1)) & 3 ; m<2 -> sl0, m>=2 -> sl1
  const int sl0 = lr + 16*((2*q4)   & 3);
  const int sl1 = lr + 16*((2*q4+1) & 3);

  // prologue: stage tile 0 into buffer 0
  {
    const int j0 = jh*1024;
    #pragma unroll
    for (int r=0;r<4;++r)
      *(uint4*)&Ks[0][(jl_k+16*r)*LDK + seg_k*8] =
        *(const uint4*)(qkv + base + (size_t)(j0 + jl_k + 16*r)*384 + 128 + seg_k*8);
    #pragma unroll
    for (int r=0;r<4;++r)
      *(uint4*)&Vt[0][(d_v+32*r)*LDV + c_v*8] =
        *(const uint4*)(vtg + (size_t)(d_v + 32*r)*4096 + j0 + c_v*8);
  }
  __syncthreads();

  for (int it=0; it<16; ++it){
    const int cur = it & 1;
    // (1) issue next tile's global loads FIRST (latency hides under compute)
    uint4 kr[4], vr[4];
    if (it < 15){
      const int jn = jh*1024 + (it+1)*64;
      #pragma unroll
      for (int r=0;r<4;++r)
        kr[r] = *(const uint4*)(qkv + base + (size_t)(jn + jl_k + 16*r)*384 + 128 + seg_k*8);
      #pragma unroll
      for (int r=0;r<4;++r)
        vr[r] = *(const uint4*)(vtg + (size_t)(d_v + 32*r)*4096 + jn + c_v*8);
    }
    // (2) QK^T on current buffer; keep exp'd P packed in registers
    unsigned pk[4][2][2];   // [jt][isub][r-half]: (r0,r1),(r2,r3) bf16 pairs
    #pragma unroll
    for (int jt=0;jt<4;++jt){
      bfrag kf[4];
      #pragma unroll
      for (int kk=0;kk<4;++kk) kf[kk] = *(const bfrag*)&Ks[cur][(jt*16+lr)*LDK + kk*32 + q4*8]; // A[m=j][k=d]
      #pragma unroll
      for (int isub=0;isub<2;++isub){
        ffrag s = {};
        #pragma unroll
        for (int kk=0;kk<4;++kk) s = MFMA(kf[kk], qf[isub][kk], s);   // D[m=j][n=i]
        pk[jt][isub][0] = bfpack(__expf(s[0]*inv64), __expf(s[1]*inv64));
        pk[jt][isub][1] = bfpack(__expf(s[2]*inv64), __expf(s[3]*inv64));
      }
    }
    // (3) PV: redistribute P via shuffles (D rows q4*4+r -> B rows q4*8+e), then MFMA
    #pragma unroll
    for (int jk=0;jk<2;++jk){
      union { bfrag b; uint4 u; } pf0, pf1;
      unsigned v0[4], v1[4];
      #pragma unroll
      for (int m=0;m<4;++m){
        const int sl = (m<2) ? sl0 : sl1;
        unsigned a0 = __shfl(pk[2*jk  ][0][m&1], sl);
        unsigned b0 = __shfl(pk[2*jk+1][0][m&1], sl);
        v0[m] = (q4 >= 2) ? b0 : a0;
        unsigned a1 = __shfl(pk[2*jk  ][1][m&1], sl);
        unsigned b1 = __shfl(pk[2*jk+1][1][m&1], sl);
        v1[m] = (q4 >= 2) ? b1 : a1;
      }
      pf0.u = make_uint4(v0[0],v0[1],v0[2],v0[3]);
      pf1.u = make_uint4(v1[0],v1[1],v1[2],v1[3]);
      #pragma unroll
      for (int dt=0;dt<8;++dt){
        bfrag af = *(const bfrag*)&Vt[cur][(dt*16+lr)*LDV + jk*32 + q4*8]; // A[m=d][k=j]
        acc[dt][0] = MFMA(af, pf0.b, acc[dt][0]);   // D[m=d][n=i]
        acc[dt][1] = MFMA(af, pf1.b, acc[dt][1]);
      }
    }
    // (4) sink staged writes into the other buffer (vmcnt drain lands here, after compute)
    if (it < 15){
      #pragma unroll
      for (int r=0;r<4;++r) *(uint4*)&Ks[cur^1][(jl_k+16*r)*LDK + seg_k*8] = kr[r];
      #pragma unroll
      for (int r=0;r<4;++r) *(uint4*)&Vt[cur^1][(d_v+32*r)*LDV + c_v*8] = vr[r];
      __syncthreads();
    }
  }
  unsigned short* po = part + (size_t)(jh*4+n)*524288;
  #pragma unroll
  for (int isub=0;isub<2;++isub){
    const int i = i0 + w*32 + isub*16 + lr;
    #pragma unroll
    for (int dt=0;dt<8;++dt){
      us4 pko;
      pko.x = f2bf(acc[dt][isub][0]); pko.y = f2bf(acc[dt][isub][1]);
      pko.z = f2bf(acc[dt][isub][2]); pko.w = f2bf(acc[dt][isub][3]);
      *(us4*)(po + (size_t)i*128 + dt*16 + q4*4) = pko;
    }
  }
}

// ---------------- K5: output projection, sums 4 bf16 partial slices (uint4 loads), c-tile 128 ----------------
__global__ __launch_bounds__(256) void k_oproj(const unsigned short* __restrict__ part,
                                               const unsigned short* __restrict__ Wob,
                                               const float* __restrict__ bo, float* __restrict__ y){
  constexpr int LD = 136;
  __shared__ __align__(16) unsigned short As[128*LD];  // Wo tile [c][e]
  __shared__ __align__(16) unsigned short Rt[64*LD];   // attn^T [hw][e]
  const int c0 = blockIdx.x*128, h0 = blockIdx.y*64, n = blockIdx.z;
  const int t = threadIdx.x, w = t>>6, lane = t&63, lr = lane&15, q4 = lane>>4;
  #pragma unroll
  for (int r=0;r<8;++r){
    int pi = t + 256*r; int cl = pi>>4, seg = pi&15;
    *(uint4*)&As[cl*LD + seg*8] = *(const uint4*)(Wob + (c0+cl)*128 + seg*8);
  }
  #pragma unroll
  for (int r=0;r<4;++r){                     // 1024 = 128 e x 8 h-octets, uint4 loads
    int pi = t + 256*r; int e = pi>>3, h8 = pi&7;
    size_t f = (size_t)e*4096 + h0 + h8*8;
    float a[8] = {};
    #pragma unroll
    for (int s=0;s<4;++s){
      uint4 u = *(const uint4*)(part + (size_t)(s*4+n)*524288 + f);
      a[0] += bf2f((unsigned short)(u.x & 0xffffu)); a[1] += bf2f((unsigned short)(u.x >> 16));
      a[2] += bf2f((unsigned short)(u.y & 0xffffu)); a[3] += bf2f((unsigned short)(u.y >> 16));
      a[4] += bf2f((unsigned short)(u.z & 0xffffu)); a[5] += bf2f((unsigned short)(u.z >> 16));
      a[6] += bf2f((unsigned short)(u.w & 0xffffu)); a[7] += bf2f((unsigned short)(u.w >> 16));
    }
    #pragma unroll
    for (int k=0;k<8;++k) Rt[(h8*8+k)*LD + e] = f2bf(a[k]);
  }
  __syncthreads();
  ffrag acc[8] = {};
  #pragma unroll
  for (int kk=0;kk<4;++kk){
    bfrag a = *(const bfrag*)&Rt[(w*16+lr)*LD + kk*32 + q4*8];   // A = attn^T rows (hw)
    #pragma unroll
    for (int cs=0;cs<8;++cs){
      bfrag b = *(const bfrag*)&As[(cs*16+lr)*LD + kk*32 + q4*8]; // B = Wo rows (c)
      acc[cs] = MFMA(a,b,acc[cs]);                                // D[m=hw][n=c]
    }
  }
  #pragma unroll
  for (int cs=0;cs<8;++cs){
    int c = c0 + cs*16 + lr;
    float bias = bo[c];
    float4 v4 = { acc[cs][0]+bias, acc[cs][1]+bias, acc[cs][2]+bias, acc[cs][3]+bias };
    *(float4*)(y + ((size_t)n*256 + c)*4096 + h0 + w*16 + q4*4) = v4;
  }
}

extern "C" void kernel_launch(void* const* d_in, const int* in_sizes, int n_in,
                              void* d_out, int out_size, void* d_ws, size_t ws_size,
                              hipStream_t stream){
  const float* x  = (const float*)d_in[0];
  const float* Wq = (const float*)d_in[1];
  const float* bq = (const float*)d_in[2];
  const float* Wo = (const float*)d_in[3];
  const float* bo = (const float*)d_in[4];
  float* y = (float*)d_out;
  char* ws = (char*)d_ws;
  unsigned short* qkv  = (unsigned short*)(ws + 0);          // 12,582,912
  unsigned short* vtg  = (unsigned short*)(ws + 12582912);   //  4,194,304
  unsigned short* Wqb  = (unsigned short*)(ws + 16777216);   //    196,608
  unsigned short* Wob  = (unsigned short*)(ws + 16973824);   //     65,536
  float* zp   = (float*)(ws + 17039360);                     //    524,288 (4n x 8ic x 4096)
  unsigned short* part = (unsigned short*)(ws + 17629184);   // 16,777,216 (16 bf16 slices jh*4+n)

  k_wcast <<<dim3(384),     256, 0, stream>>>(Wq, Wo, Wqb, Wob);
  k_qkv   <<<dim3(3,64,4),  256, 0, stream>>>(x, Wqb, bq, qkv);
  k_stats <<<dim3(16,8,4),  256, 0, stream>>>(qkv, zp);
  k_vtrans<<<dim3(64,4),    256, 0, stream>>>(qkv, zp, vtg);
  k_attn  <<<dim3(32,4,4),  256, 0, stream>>>(qkv, vtg, part);
  k_oproj <<<dim3(2,64,4),  256, 0, stream>>>(part, Wob, bo, y);
}